// Round 1
// baseline (72.999 us; speedup 1.0000x reference)
//
#include <hip/hip_runtime.h>

namespace {

constexpr int R   = 4;            // radius = int(4*1 + 0.5)
constexpr int TS  = 64;           // output tile edge
constexpr int HS  = TS + 2 * R;   // 72 = tile + halo
constexpr int LSTR = HS + 1;      // 73, padded LDS row stride
constexpr int IMG_H = 512;
constexpr int IMG_W = 512;

__global__ __launch_bounds__(256)
void gauss_blur_kernel(const float* __restrict__ in, float* __restrict__ out) {
    // Normalized gaussian taps for sigma=1, radius=4 (float32, matches numpy
    // normalization well within the 1.77e-2 absmax threshold).
    const float KW[9] = {
        1.3383062e-4f, 4.4318616e-3f, 5.3990966e-2f, 2.4197144e-1f,
        3.9894347e-1f, 2.4197144e-1f, 5.3990966e-2f, 4.4318616e-3f,
        1.3383062e-4f};

    __shared__ float s_in[HS * LSTR];  // input tile + halo (72 x 72)
    __shared__ float s_v [TS * LSTR];  // after vertical pass (64 x 72)

    const int tid = threadIdx.x;
    const int b   = blockIdx.z;
    const int ty0 = blockIdx.y * TS;
    const int tx0 = blockIdx.x * TS;

    const float* __restrict__ inb = in + (size_t)b * IMG_H * IMG_W;

    // ---- stage input tile + halo, edge-clamped ("nearest" padding) ----
    for (int i = tid; i < HS * HS; i += 256) {
        int ly = i / HS;
        int lx = i - ly * HS;
        int gy = ty0 + ly - R;
        gy = gy < 0 ? 0 : (gy > IMG_H - 1 ? IMG_H - 1 : gy);
        int gx = tx0 + lx - R;
        gx = gx < 0 ? 0 : (gx > IMG_W - 1 ? IMG_W - 1 : gx);
        s_in[ly * LSTR + lx] = inb[gy * IMG_W + gx];
    }
    __syncthreads();

    // ---- vertical 9-tap pass: (72 wide) x (64 tall) ----
    for (int i = tid; i < TS * HS; i += 256) {
        int ly = i / HS;
        int lx = i - ly * HS;
        float acc = 0.f;
        #pragma unroll
        for (int t = 0; t < 9; ++t)
            acc = fmaf(KW[t], s_in[(ly + t) * LSTR + lx], acc);
        s_v[ly * LSTR + lx] = acc;
    }
    __syncthreads();

    // ---- horizontal 9-tap pass + coalesced store ----
    float* __restrict__ outb = out + (size_t)b * IMG_H * IMG_W;
    for (int i = tid; i < TS * TS; i += 256) {
        int ly = i >> 6;          // /64
        int lx = i & (TS - 1);    // %64
        float acc = 0.f;
        #pragma unroll
        for (int t = 0; t < 9; ++t)
            acc = fmaf(KW[t], s_v[ly * LSTR + lx + t], acc);
        outb[(ty0 + ly) * IMG_W + (tx0 + lx)] = acc;
    }
}

}  // namespace

extern "C" void kernel_launch(void* const* d_in, const int* in_sizes, int n_in,
                              void* d_out, int out_size, void* d_ws, size_t ws_size,
                              hipStream_t stream) {
    const float* x = (const float*)d_in[0];
    float* out = (float*)d_out;

    const int batch = in_sizes[0] / (IMG_H * IMG_W);  // 128

    dim3 grid(IMG_W / TS, IMG_H / TS, batch);         // (8, 8, 128)
    gauss_blur_kernel<<<grid, 256, 0, stream>>>(x, out);
}

// Round 2
// 62.122 us; speedup vs baseline: 1.1751x; 1.1751x over previous
//
#include <hip/hip_runtime.h>

namespace {

constexpr int R     = 4;          // radius = int(4*1 + 0.5)
constexpr int TSX   = 64;         // output tile width
constexpr int TSY   = 32;         // output tile height
constexpr int HSX   = TSX + 2*R;  // 72 = staged width
constexpr int HSY   = TSY + 2*R;  // 40 = staged height
constexpr int VSTR  = 76;         // LDS row stride (floats): 304 B, 16B-aligned, 12-bank row skew
constexpr int NVX   = HSX / 4;    // 18 float4 per staged row
constexpr int IMG_H = 512;
constexpr int IMG_W = 512;

__device__ __forceinline__ int clampi(int v, int lo, int hi) {
    return v < lo ? lo : (v > hi ? hi : v);
}

__global__ __launch_bounds__(256)
void gauss_blur_kernel(const float* __restrict__ in, float* __restrict__ out) {
    const float KW[9] = {
        1.3383062e-4f, 4.4318616e-3f, 5.3990966e-2f, 2.4197144e-1f,
        3.9894347e-1f, 2.4197144e-1f, 5.3990966e-2f, 4.4318616e-3f,
        1.3383062e-4f};

    __shared__ float s_in[HSY * VSTR];  // 40 x 72 staged input (12160 B)
    __shared__ float s_v [TSY * VSTR];  // 32 x 72 vertical result (9728 B)

    const int tid = threadIdx.x;
    const int b   = blockIdx.z;
    const int ty0 = blockIdx.y * TSY;
    const int tx0 = blockIdx.x * TSX;

    const float* __restrict__ inb = in + (size_t)b * IMG_H * IMG_W;

    // ---- stage 72x40 halo tile, float4 loads, edge-clamped ----
    for (int i = tid; i < HSY * NVX; i += 256) {
        int ly = i / NVX;
        int v  = i - ly * NVX;
        int gy = clampi(ty0 + ly - R, 0, IMG_H - 1);
        int gx = tx0 - R + 4 * v;
        const float* rp = inb + gy * IMG_W;
        float4 val;
        if (gx >= 0 && gx <= IMG_W - 4) {
            val = *reinterpret_cast<const float4*>(rp + gx);
        } else {  // only first/last x-tiles' edge vectors take this path
            val.x = rp[clampi(gx + 0, 0, IMG_W - 1)];
            val.y = rp[clampi(gx + 1, 0, IMG_W - 1)];
            val.z = rp[clampi(gx + 2, 0, IMG_W - 1)];
            val.w = rp[clampi(gx + 3, 0, IMG_W - 1)];
        }
        *reinterpret_cast<float4*>(&s_in[ly * VSTR + 4 * v]) = val;
    }
    __syncthreads();

    // ---- vertical 9-tap pass: 72 wide x 32 tall, float4 ----
    for (int i = tid; i < TSY * NVX; i += 256) {
        int ly = i / NVX;
        int v  = i - ly * NVX;
        float4 acc = {0.f, 0.f, 0.f, 0.f};
        #pragma unroll
        for (int t = 0; t < 9; ++t) {
            float4 a = *reinterpret_cast<const float4*>(&s_in[(ly + t) * VSTR + 4 * v]);
            acc.x = fmaf(KW[t], a.x, acc.x);
            acc.y = fmaf(KW[t], a.y, acc.y);
            acc.z = fmaf(KW[t], a.z, acc.z);
            acc.w = fmaf(KW[t], a.w, acc.w);
        }
        *reinterpret_cast<float4*>(&s_v[ly * VSTR + 4 * v]) = acc;
    }
    __syncthreads();

    // ---- horizontal 9-tap pass: each thread makes 4 outputs from 12 LDS floats ----
    float* __restrict__ outb = out + (size_t)b * IMG_H * IMG_W;
    for (int i = tid; i < TSY * (TSX / 4); i += 256) {
        int ly = i >> 4;          // / 16
        int j  = i & 15;          // % 16
        const float* vp = &s_v[ly * VSTR + 4 * j];
        float4 a = *reinterpret_cast<const float4*>(vp);
        float4 bq = *reinterpret_cast<const float4*>(vp + 4);
        float4 c = *reinterpret_cast<const float4*>(vp + 8);
        float w[12] = {a.x, a.y, a.z, a.w, bq.x, bq.y, bq.z, bq.w, c.x, c.y, c.z, c.w};
        float4 o;
        float acc0 = 0.f, acc1 = 0.f, acc2 = 0.f, acc3 = 0.f;
        #pragma unroll
        for (int t = 0; t < 9; ++t) {
            acc0 = fmaf(KW[t], w[t + 0], acc0);
            acc1 = fmaf(KW[t], w[t + 1], acc1);
            acc2 = fmaf(KW[t], w[t + 2], acc2);
            acc3 = fmaf(KW[t], w[t + 3], acc3);
        }
        o.x = acc0; o.y = acc1; o.z = acc2; o.w = acc3;
        *reinterpret_cast<float4*>(&outb[(ty0 + ly) * IMG_W + tx0 + 4 * j]) = o;
    }
}

}  // namespace

extern "C" void kernel_launch(void* const* d_in, const int* in_sizes, int n_in,
                              void* d_out, int out_size, void* d_ws, size_t ws_size,
                              hipStream_t stream) {
    const float* x = (const float*)d_in[0];
    float* out = (float*)d_out;

    const int batch = in_sizes[0] / (IMG_H * IMG_W);  // 128

    dim3 grid(IMG_W / TSX, IMG_H / TSY, batch);       // (8, 16, 128)
    gauss_blur_kernel<<<grid, 256, 0, stream>>>(x, out);
}